// Round 1
// baseline (161.134 us; speedup 1.0000x reference)
//
#include <hip/hip_runtime.h>
#include <hip/hip_bf16.h>

typedef unsigned short u16;
typedef __attribute__((ext_vector_type(8))) short short8;
typedef __attribute__((ext_vector_type(4))) float floatx4;

#define NROWS 8192
#define DIM 256
#define BM 128
#define BN 128
#define BK 32

__device__ __forceinline__ void atomicMinFloat(float* addr, float val) {
    if (val >= 0.0f) {
        atomicMin((int*)addr, __float_as_int(val));
    } else {
        atomicMax((unsigned int*)addr, __float_as_uint(val));
    }
}

__device__ __forceinline__ u16 f32_to_bf16_rne(float x) {
    unsigned int u = __float_as_uint(x);
    unsigned int r = (u + 0x7fffu + ((u >> 16) & 1u)) >> 16;
    return (u16)r;
}

__global__ __launch_bounds__(256) void init_out(float* __restrict__ out) {
    int i = blockIdx.x * 256 + threadIdx.x;
    if (i < NROWS) out[i] = __uint_as_float(0x7f800000u);  // +inf
}

// One block per row (grid.y selects Ex vs Ey). Normalize row to unit L2
// (norm clamped at 1e-8, matching torch CosineSimilarity eps), store bf16.
__global__ __launch_bounds__(256) void normalize_kernel(const float* __restrict__ Ex,
                                                        const float* __restrict__ Ey,
                                                        u16* __restrict__ Xn,
                                                        u16* __restrict__ Yn) {
    const int row = blockIdx.x;
    const int t = threadIdx.x;
    const float* src = (blockIdx.y == 0) ? Ex : Ey;
    u16* dst = (blockIdx.y == 0) ? Xn : Yn;

    float v = src[(size_t)row * DIM + t];
    float s = v * v;
    #pragma unroll
    for (int m = 32; m >= 1; m >>= 1) s += __shfl_xor(s, m, 64);

    __shared__ float wsum[4];
    const int wid = t >> 6;
    if ((t & 63) == 0) wsum[wid] = s;
    __syncthreads();
    float total = wsum[0] + wsum[1] + wsum[2] + wsum[3];
    float inv = 1.0f / fmaxf(sqrtf(total), 1e-8f);
    dst[(size_t)row * DIM + t] = f32_to_bf16_rne(v * inv);
}

// 128x128 block tile, BK=32, 4 waves in 2x2, each wave computes 64x64 via
// 4x4 grid of 16x16x32 bf16 MFMAs. Fused epilogue: C(M) = -p*logp with
// p = N(1, 0.3).pdf(M), min over this block's 128 columns per row, atomicMin.
__global__ __launch_bounds__(256) void gemm_min_kernel(const u16* __restrict__ Xn,
                                                       const u16* __restrict__ Yn,
                                                       float* __restrict__ out) {
    __shared__ u16 As[BM * BK];
    __shared__ u16 Bs[BN * BK];

    const int tid = threadIdx.x;
    const int rowStart = blockIdx.y * BM;
    const int colStart = blockIdx.x * BN;
    const int wid = tid >> 6;
    const int lane = tid & 63;
    const int wr = wid >> 1;   // wave row (0..1) -> 64 rows
    const int wc = wid & 1;    // wave col (0..1) -> 64 cols
    const int lq = lane >> 4;  // quad 0..3
    const int lm = lane & 15;

    floatx4 acc[4][4];
    #pragma unroll
    for (int i = 0; i < 4; ++i)
        #pragma unroll
        for (int j = 0; j < 4; ++j)
            acc[i][j] = (floatx4){0.0f, 0.0f, 0.0f, 0.0f};

    // staging: 512 chunks of 16B per tile; chunk c -> row c>>2, 16B piece c&3
    const int c0 = tid;
    const int c1 = tid + 256;

    for (int kt = 0; kt < DIM / BK; ++kt) {
        const int k0 = kt * BK;
        const uint4 va0 = *(const uint4*)(Xn + (size_t)(rowStart + (c0 >> 2)) * DIM + k0 + (c0 & 3) * 8);
        const uint4 va1 = *(const uint4*)(Xn + (size_t)(rowStart + (c1 >> 2)) * DIM + k0 + (c1 & 3) * 8);
        const uint4 vb0 = *(const uint4*)(Yn + (size_t)(colStart + (c0 >> 2)) * DIM + k0 + (c0 & 3) * 8);
        const uint4 vb1 = *(const uint4*)(Yn + (size_t)(colStart + (c1 >> 2)) * DIM + k0 + (c1 & 3) * 8);
        ((uint4*)As)[c0] = va0;
        ((uint4*)As)[c1] = va1;
        ((uint4*)Bs)[c0] = vb0;
        ((uint4*)Bs)[c1] = vb1;
        __syncthreads();

        short8 a[4], b[4];
        #pragma unroll
        for (int rg = 0; rg < 4; ++rg)
            a[rg] = *(const short8*)(As + (wr * 64 + rg * 16 + lm) * BK + lq * 8);
        #pragma unroll
        for (int cg = 0; cg < 4; ++cg)
            b[cg] = *(const short8*)(Bs + (wc * 64 + cg * 16 + lm) * BK + lq * 8);

        #pragma unroll
        for (int rg = 0; rg < 4; ++rg)
            #pragma unroll
            for (int cg = 0; cg < 4; ++cg)
                acc[rg][cg] = __builtin_amdgcn_mfma_f32_16x16x32_bf16(a[rg], b[cg], acc[rg][cg], 0, 0, 0);
        __syncthreads();
    }

    // Epilogue: C(M) = -p*logp, p = exp(logp), logp = -0.5*z^2 - ln(sigma) - ln(sqrt(2pi))
    const float INV_SIG = 1.0f / 0.3f;
    const float KC = 0.28503427f;  // -ln(0.3) - 0.5*ln(2*pi)
    #pragma unroll
    for (int rg = 0; rg < 4; ++rg) {
        #pragma unroll
        for (int r = 0; r < 4; ++r) {
            float mv = 3.4e38f;
            #pragma unroll
            for (int cg = 0; cg < 4; ++cg) {
                float m = acc[rg][cg][r];
                float z = (m - 1.0f) * INV_SIG;
                float logp = fmaf(-0.5f * z, z, KC);
                float p = __expf(logp);
                float c = -p * logp;
                mv = fminf(mv, c);
            }
            // min across the 16 lanes of this quad (covers 4 cg x 16 cols = 64 cols)
            #pragma unroll
            for (int mofs = 1; mofs < 16; mofs <<= 1)
                mv = fminf(mv, __shfl_xor(mv, mofs, 64));
            if (lm == 0) {
                int row = rowStart + wr * 64 + rg * 16 + lq * 4 + r;
                atomicMinFloat(&out[row], mv);
            }
        }
    }
}

extern "C" void kernel_launch(void* const* d_in, const int* in_sizes, int n_in,
                              void* d_out, int out_size, void* d_ws, size_t ws_size,
                              hipStream_t stream) {
    const float* Ex = (const float*)d_in[0];
    const float* Ey = (const float*)d_in[1];
    float* out = (float*)d_out;
    u16* Xn = (u16*)d_ws;                       // 8192*256 bf16 = 4 MB
    u16* Yn = Xn + (size_t)NROWS * DIM;         // next 4 MB

    hipLaunchKernelGGL(init_out, dim3(NROWS / 256), dim3(256), 0, stream, out);
    hipLaunchKernelGGL(normalize_kernel, dim3(NROWS, 2), dim3(256), 0, stream, Ex, Ey, Xn, Yn);
    hipLaunchKernelGGL(gemm_min_kernel, dim3(NROWS / BN, NROWS / BM), dim3(256), 0, stream,
                       Xn, Yn, out);
}

// Round 2
// 154.296 us; speedup vs baseline: 1.0443x; 1.0443x over previous
//
#include <hip/hip_runtime.h>
#include <hip/hip_bf16.h>

typedef unsigned short u16;
typedef __attribute__((ext_vector_type(8))) short short8;
typedef __attribute__((ext_vector_type(4))) float floatx4;

#define NROWS 8192
#define DIM 256
#define BM 128
#define BN 128
#define BK 32

__device__ __forceinline__ void atomicMinFloat(float* addr, float val) {
    if (val >= 0.0f) {
        atomicMin((int*)addr, __float_as_int(val));
    } else {
        atomicMax((unsigned int*)addr, __float_as_uint(val));
    }
}

__device__ __forceinline__ u16 f32_to_bf16_rne(float x) {
    unsigned int u = __float_as_uint(x);
    unsigned int r = (u + 0x7fffu + ((u >> 16) & 1u)) >> 16;
    return (u16)r;
}

// C(M) = -logp * exp(logp), logp = -0.5*((M-1)/sigma)^2 - ln(sigma) - 0.5 ln(2pi)
__device__ __forceinline__ float c_of_m(float m) {
    const float INV_SIG = 1.0f / 0.3f;
    const float KC = 0.28503427f;  // -ln(0.3) - 0.5*ln(2*pi)
    float z = (m - 1.0f) * INV_SIG;
    float logp = fmaf(-0.5f * z, z, KC);
    return -logp * __expf(logp);
}

// 16B async DMA global -> LDS. LDS dest is wave-uniform base + lane*16.
__device__ __forceinline__ void load16(const u16* g, u16* l) {
    __builtin_amdgcn_global_load_lds(
        (__attribute__((address_space(1))) void*)g,
        (__attribute__((address_space(3))) void*)l, 16, 0, 0);
}

// Wave-per-row normalize: 4 rows/block, float4 loads, shuffle reduce, bf16 out.
// Also initializes out[] to +inf (fused init).
__global__ __launch_bounds__(256) void normalize_kernel(const float* __restrict__ Ex,
                                                        const float* __restrict__ Ey,
                                                        u16* __restrict__ Xn,
                                                        u16* __restrict__ Yn,
                                                        float* __restrict__ out) {
    const int t = threadIdx.x;
    const int lane = t & 63;
    const int row = blockIdx.x * 4 + (t >> 6);
    const float* src = (blockIdx.y == 0) ? Ex : Ey;
    u16* dst = (blockIdx.y == 0) ? Xn : Yn;

    float4 v = *(const float4*)(src + (size_t)row * DIM + lane * 4);
    float s = fmaf(v.x, v.x, fmaf(v.y, v.y, fmaf(v.z, v.z, v.w * v.w)));
    #pragma unroll
    for (int m = 32; m >= 1; m >>= 1) s += __shfl_xor(s, m, 64);
    float inv = 1.0f / fmaxf(sqrtf(s), 1e-8f);

    u16* dp = dst + (size_t)row * DIM + lane * 4;
    ushort4 o;
    o.x = f32_to_bf16_rne(v.x * inv);
    o.y = f32_to_bf16_rne(v.y * inv);
    o.z = f32_to_bf16_rne(v.z * inv);
    o.w = f32_to_bf16_rne(v.w * inv);
    *(ushort4*)dp = o;

    if (blockIdx.y == 0 && lane == 0) out[row] = __uint_as_float(0x7f800000u);  // +inf
}

// Stage one 128x32 A-tile and B-tile (bf16) into LDS via global_load_lds.
// LDS chunk s (16B) holds (row = s>>2, piece = (s&3) ^ ((row>>1)&3)) -- the
// xor swizzle makes ds_read_b128 fragment reads 2-way-conflict-free while
// keeping the 4 lanes of a row within one 64B global segment.
__device__ __forceinline__ void stage_tile(const u16* __restrict__ X,
                                           const u16* __restrict__ Y,
                                           int rowStart, int colStart, int k0,
                                           u16* As, u16* Bs, int w, int lane) {
    #pragma unroll
    for (int i = 0; i < 2; ++i) {
        const int s = i * 256 + w * 64 + lane;
        const int row = s >> 2;
        const int pg = (s & 3) ^ ((row >> 1) & 3);
        const u16* gA = X + (size_t)(rowStart + row) * DIM + k0 + pg * 8;
        const u16* gB = Y + (size_t)(colStart + row) * DIM + k0 + pg * 8;
        u16* lA = As + (i * 256 + w * 64) * 8;  // wave-uniform base; DMA adds lane*16B
        u16* lB = Bs + (i * 256 + w * 64) * 8;
        load16(gA, lA);
        load16(gB, lB);
    }
}

// 128x128 block tile, BK=32, 4 waves 2x2 (64x64 each, 4x4 grid of
// 16x16x32 bf16 MFMA). Double-buffered LDS; prefetch issued AFTER the
// barrier so the compiler's vmcnt(0)-before-barrier only drains the
// previous tile's DMA. Epilogue tracks row min/max of M (C is quasiconcave
// in M), evaluates C twice per row, atomicMin into out.
__global__ __launch_bounds__(256) void gemm_min_kernel(const u16* __restrict__ Xn,
                                                       const u16* __restrict__ Yn,
                                                       float* __restrict__ out) {
    __shared__ u16 As[2][512 * 8];  // 2 x 8 KB
    __shared__ u16 Bs[2][512 * 8];  // 2 x 8 KB

    const int tid = threadIdx.x;
    const int rowStart = blockIdx.y * BM;
    const int colStart = blockIdx.x * BN;
    const int w = tid >> 6;
    const int lane = tid & 63;
    const int wr = w >> 1;
    const int wc = w & 1;
    const int lq = lane >> 4;
    const int lm = lane & 15;
    const int swz = (lm >> 1) & 3;

    floatx4 acc[4][4];
    #pragma unroll
    for (int i = 0; i < 4; ++i)
        #pragma unroll
        for (int j = 0; j < 4; ++j)
            acc[i][j] = (floatx4){0.0f, 0.0f, 0.0f, 0.0f};

    stage_tile(Xn, Yn, rowStart, colStart, 0, As[0], Bs[0], w, lane);

    #pragma unroll
    for (int kt = 0; kt < DIM / BK; ++kt) {
        const int cur = kt & 1;
        __syncthreads();  // compiler-inserted vmcnt(0) waits on tile-kt DMA only
        if (kt < DIM / BK - 1)
            stage_tile(Xn, Yn, rowStart, colStart, (kt + 1) * BK,
                       As[cur ^ 1], Bs[cur ^ 1], w, lane);

        short8 a[4], b[4];
        #pragma unroll
        for (int rg = 0; rg < 4; ++rg) {
            const int r = wr * 64 + rg * 16 + lm;
            a[rg] = *(const short8*)(As[cur] + (((r << 2) + (lq ^ swz)) << 3));
        }
        #pragma unroll
        for (int cg = 0; cg < 4; ++cg) {
            const int r = wc * 64 + cg * 16 + lm;
            b[cg] = *(const short8*)(Bs[cur] + (((r << 2) + (lq ^ swz)) << 3));
        }

        #pragma unroll
        for (int rg = 0; rg < 4; ++rg)
            #pragma unroll
            for (int cg = 0; cg < 4; ++cg)
                acc[rg][cg] = __builtin_amdgcn_mfma_f32_16x16x32_bf16(a[rg], b[cg], acc[rg][cg], 0, 0, 0);
    }

    // Epilogue: row min/max of M over this block's 128 columns.
    #pragma unroll
    for (int rg = 0; rg < 4; ++rg) {
        #pragma unroll
        for (int r = 0; r < 4; ++r) {
            float mn = acc[rg][0][r];
            float mx = mn;
            #pragma unroll
            for (int cg = 1; cg < 4; ++cg) {
                float m = acc[rg][cg][r];
                mn = fminf(mn, m);
                mx = fmaxf(mx, m);
            }
            #pragma unroll
            for (int mofs = 1; mofs < 16; mofs <<= 1) {
                mn = fminf(mn, __shfl_xor(mn, mofs, 64));
                mx = fmaxf(mx, __shfl_xor(mx, mofs, 64));
            }
            float cmin = fminf(c_of_m(mn), c_of_m(mx));
            if (lm == 0) {
                int row = rowStart + wr * 64 + rg * 16 + lq * 4 + r;
                atomicMinFloat(&out[row], cmin);
            }
        }
    }
}

extern "C" void kernel_launch(void* const* d_in, const int* in_sizes, int n_in,
                              void* d_out, int out_size, void* d_ws, size_t ws_size,
                              hipStream_t stream) {
    const float* Ex = (const float*)d_in[0];
    const float* Ey = (const float*)d_in[1];
    float* out = (float*)d_out;
    u16* Xn = (u16*)d_ws;                // 4 MB
    u16* Yn = Xn + (size_t)NROWS * DIM;  // 4 MB

    hipLaunchKernelGGL(normalize_kernel, dim3(NROWS / 4, 2), dim3(256), 0, stream,
                       Ex, Ey, Xn, Yn, out);
    hipLaunchKernelGGL(gemm_min_kernel, dim3(NROWS / BN, NROWS / BM), dim3(256), 0, stream,
                       Xn, Yn, out);
}